// Round 8
// baseline (647.257 us; speedup 1.0000x reference)
//
#include <hip/hip_runtime.h>

#define L_SEQ 2048
#define DMODEL 2048
#define NHEAD 16
#define HDIM 128
#define BATCH 4

typedef _Float16 f16x8 __attribute__((ext_vector_type(8)));
typedef _Float16 f16x4 __attribute__((ext_vector_type(4)));
typedef float f32x4 __attribute__((ext_vector_type(4)));

// async global->LDS, 16B per lane. LDS base must be wave-uniform; HW scatters lane*16.
__device__ __forceinline__ void gload16(const void* g, void* l) {
  __builtin_amdgcn_global_load_lds((const __attribute__((address_space(1))) void*)g,
                                   (__attribute__((address_space(3))) void*)l, 16, 0, 0);
}

// fp32 row-major [M][K] -> fp16 blocked tile-image layout:
// tile (mb, kt) of 128 rows x 64 k, stored contiguously (8192 halves = 16KB) in LDS image
// order: 16B-unit index (kb*128 + row), kb = (k&63)>>3, within-unit = k&7.
__global__ __launch_bounds__(256) void cvt_blocked(const float* __restrict__ in,
                                                   _Float16* __restrict__ out, int K) {
  const int kt = blockIdx.x, mb = blockIdx.y, KT = K >> 6;
  const int t = threadIdx.x, row = t >> 1, half = t & 1;
  const float* src = in + (size_t)(mb * 128 + row) * K + kt * 64 + half * 32;
  _Float16* tile = out + ((size_t)mb * KT + kt) * 8192;
  for (int j = 0; j < 4; ++j) {
    float4 a = *(const float4*)(src + j * 8);
    float4 b = *(const float4*)(src + j * 8 + 4);
    f16x8 o;
    o[0] = (_Float16)a.x; o[1] = (_Float16)a.y; o[2] = (_Float16)a.z; o[3] = (_Float16)a.w;
    o[4] = (_Float16)b.x; o[5] = (_Float16)b.y; o[6] = (_Float16)b.z; o[7] = (_Float16)b.w;
    int kb = half * 4 + j;
    *(f16x8*)(tile + (size_t)(kb * 128 + row) * 8) = o;
  }
}

// C[M][N] = A * Bt^T, A/Bt in BLOCKED tile-image layout (see cvt_blocked), C row-major.
// R10: 256x256 tile, BK=64, 512 threads (8 waves, 2M x 4N), per-wave 128x64 output
// (acc[8][4] f32x4 = 128 VGPR). LDS 128 KiB double-buffered (1 block/CU, 8 waves).
// R5/R7 post-mortem: 128-sq cannot be pipelined (dbuf kills occupancy m132-style;
// kk-split's 1-phase prefetch distance exposes latency; barrier-per-16-MFMA too dense).
// This structure: ONE barrier + ONE vmcnt wait per K-tile of 64 MFMA/wave, and all 8
// staging loads of tile t+1 issue at the TOP of tile t (~600-700cy before the wait) ->
// L2 latency fully covered. Blocked layout keeps ds_read conflict-free (measured 0).
// Sync ledger: prologue stage(0)+vmcnt(0)+barrier. Iter: stage(t+1,cur^1) [8 loads];
// sched_barrier; compute 64 MFMA from buf cur; vmcnt(0) (t+1 landed; t+2 not yet
// issued); barrier (also proves all waves done reading cur -> safe to overwrite next
// iter); cur^=1. Grids exact (no divergent return); barrier count uniform.
template <typename OUT>
__global__ __launch_bounds__(512, 2) void gemm_bt(const _Float16* __restrict__ A,
                                                  const _Float16* __restrict__ Bt,
                                                  OUT* __restrict__ C,
                                                  int M, int N, int K) {
  __shared__ _Float16 As[2][2][8192];  // [buf][m-image][16KB image]
  __shared__ _Float16 Bs[2][2][8192];  // [buf][n-image][16KB image]
  const int KT = K >> 6;
  const int tid = threadIdx.x;
  const int wave = tid >> 6, lane = tid & 63, quad = lane >> 4, l15 = lane & 15;
  const int wr = wave >> 2, wc = wave & 3;  // wave -> (M-half, N-quarter)
  // bijective XCD swizzle (nwg % 8 == 0 for both call sites); tm-fast within an XCD so
  // consecutive blocks share the B panel (1 MiB) in that XCD's L2.
  const int cpx = gridDim.x >> 3;
  const int wgid = ((int)blockIdx.x & 7) * cpx + ((int)blockIdx.x >> 3);
  const int MT = M >> 8;
  const int tm = wgid % MT, tn = wgid / MT;

  // stage both A images (2tm,2tm+1) and both B images (2tn,2tn+1) of K-tile t: 8 gload16
  auto stage = [&](int t, int buf) {
    for (int i = 0; i < 2; ++i) {
      const char* srcA = (const char*)(A + ((size_t)(2 * tm + i) * KT + t) * 8192);
      const char* srcB = (const char*)(Bt + ((size_t)(2 * tn + i) * KT + t) * 8192);
      char* dstA = (char*)&As[buf][i][0];
      char* dstB = (char*)&Bs[buf][i][0];
      for (int j = 0; j < 2; ++j) {
        int off = (wave * 2 + j) * 1024;
        gload16(srcA + off + lane * 16, dstA + off);
        gload16(srcB + off + lane * 16, dstB + off);
      }
    }
  };

  f32x4 acc[8][4] = {};
  stage(0, 0);
  asm volatile("s_waitcnt vmcnt(0)" ::: "memory");
  __builtin_amdgcn_sched_barrier(0);
  __builtin_amdgcn_s_barrier();
  int cur = 0;
  const int brow = (wc & 1) * 64;
  for (int t = 0; t < KT; ++t) {
    if (t + 1 < KT) stage(t + 1, cur ^ 1);  // issue early: ~4 phases before the wait
    __builtin_amdgcn_sched_barrier(0);      // pin load-issue above compute
    const f16x8* A8 = (const f16x8*)&As[cur][wr][0];
    const f16x8* B8 = (const f16x8*)&Bs[cur][wc >> 1][0];
    for (int kk = 0; kk < 2; ++kk) {
      int kb = kk * 4 + quad;
      f16x8 bf[4];
      for (int ni = 0; ni < 4; ++ni) bf[ni] = B8[kb * 128 + brow + ni * 16 + l15];
      for (int mh = 0; mh < 2; ++mh) {
        f16x8 af[4];
        for (int mi = 0; mi < 4; ++mi) af[mi] = A8[kb * 128 + mh * 64 + mi * 16 + l15];
        __builtin_amdgcn_s_setprio(1);
        for (int mi = 0; mi < 4; ++mi)
          for (int ni = 0; ni < 4; ++ni)
            acc[mh * 4 + mi][ni] =
                __builtin_amdgcn_mfma_f32_16x16x32_f16(af[mi], bf[ni], acc[mh * 4 + mi][ni], 0, 0, 0);
        __builtin_amdgcn_s_setprio(0);
      }
    }
    asm volatile("s_waitcnt vmcnt(0)" ::: "memory");  // t+1 landed (issued ~700cy ago)
    __builtin_amdgcn_sched_barrier(0);
    __builtin_amdgcn_s_barrier();  // + all waves done reading cur
    cur ^= 1;
  }
  // C/D layout: col = lane&15, row = quad*4 + reg  (m89-verified, dtype-independent)
  for (int a = 0; a < 8; ++a)
    for (int ni = 0; ni < 4; ++ni) {
      int r = tm * 256 + wr * 128 + (a >> 2) * 64 + (a & 3) * 16 + quad * 4;
      int c = tn * 256 + wc * 64 + ni * 16 + l15;
      for (int reg = 0; reg < 4; ++reg)
        C[(size_t)(r + reg) * N + c] = (OUT)acc[a][ni][reg];
    }
}

// qkv[8192][6144] fp16, q/k part only -> rope -> qt,kt:[bh][l][hd]   (coalesced both sides)
__global__ void rope_scatter(const _Float16* __restrict__ qkv,
                             _Float16* __restrict__ qt,
                             _Float16* __restrict__ kt) {
  int row = blockIdx.x;                       // 0..8191 = b*2048 + l
  int pe = blockIdx.y * 256 + threadIdx.x;    // 0..2047 pair index (q,k only)
  int e = pe * 2;
  float x1 = (float)qkv[(size_t)row * 6144 + e];
  float x2 = (float)qkv[(size_t)row * 6144 + e + 1];
  int which = e >> 11;                        // 0=q, 1=k
  int h = (e >> 7) & 15;
  int hd = e & 127;
  int b = row >> 11, l = row & 2047;
  int bh = b * 16 + h;
  int i = hd >> 1;
  // freq = 10000^(-i/64) ; ln(10000)/64 = 0.14391156831212787
  float ang = (float)l * __expf((float)i * -0.14391156831212787f);
  float s, c;
  __sincosf(ang, &s, &c);
  float o1 = x1 * c - x2 * s;
  float o2 = x2 * c + x1 * s;
  _Float16* dst = (which == 0) ? qt : kt;
  size_t base = ((size_t)bh * 2048 + l) * 128 + hd;
  dst[base] = (_Float16)o1;
  dst[base + 1] = (_Float16)o2;
}

// V part of qkv -> vt[bh][hd][l], LDS-tiled 64x64 transpose, coalesced global R/W.
__global__ __launch_bounds__(256) void v_transpose(const _Float16* __restrict__ qkv,
                                                   _Float16* __restrict__ vt) {
  __shared__ _Float16 Ls[64 * 72];
  const int tid = threadIdx.x;
  const int l0 = blockIdx.x * 64;       // 32 tiles
  const int hd0 = blockIdx.y * 64;      // 2 tiles
  const int bh = blockIdx.z;            // 64
  const int b = bh >> 4, h = bh & 15;
  const size_t colbase = 4096 + h * 128 + hd0;
  for (int i = 0; i < 2; ++i) {
    int chunk = tid + i * 256;
    int r = chunk >> 3, c = chunk & 7;
    f16x8 v = *(const f16x8*)(qkv + (size_t)(b * 2048 + l0 + r) * 6144 + colbase + c * 8);
    *(f16x8*)(Ls + r * 72 + c * 8) = v;
  }
  __syncthreads();
  for (int i = 0; i < 2; ++i) {
    int chunk = tid + i * 256;
    int hr = chunk >> 3, c = chunk & 7;
    f16x8 o;
    for (int j = 0; j < 8; ++j) o[j] = Ls[(c * 8 + j) * 72 + hr];
    *(f16x8*)(vt + ((size_t)bh * 128 + hd0 + hr) * 2048 + l0 + c * 8) = o;
  }
}

// Flash attention, causal. 8-wave blocks, 128 q rows, KV tiles of 64.
// Grid (64,16) (bh fast-moving) + mod-4-balanced perm so each stride-4 residue class of
// blockIdx.y sums to identical work (68 tile-units/CU exact), longest classes first.
//   perm = [15,14,13,12, 8,9,10,11, 4,5,6,7, 3,2,1,0]
// Q pre-scaled by 1/sqrt(128); causal mask only on the two diagonal tiles.
// Per-wave vmcnt ledger (2 K + 2 V gloads per wave per tile, K before V):
//   loop top: [K_t(2), V_t(2)]          -> vmcnt(2) = K_t landed
//   mid (after stageK(t+1)): [V_t(2), K_t+1(2)] -> vmcnt(2) = V_t landed (last tile: 0)
//   end (after stageV(t+1)): [K_t+1(2), V_t+1(2)] -> loop-top invariant
__global__ __launch_bounds__(512, 4) void attn_fwd(const _Float16* __restrict__ qt,
                                                   const _Float16* __restrict__ kt,
                                                   const _Float16* __restrict__ vt,
                                                   _Float16* __restrict__ y) {
  __shared__ _Float16 Kl[64 * 128];      // 16KB
  __shared__ _Float16 Vl[64 * 128];      // 16KB
  __shared__ _Float16 Pl[8 * 16 * 64];   // 16KB
  const int a = blockIdx.y >> 2, bq = blockIdx.y & 3;
  const int qb = (a == 0) ? 15 - bq : (a == 1) ? 8 + bq : (a == 2) ? 4 + bq : 3 - bq;
  const int q0 = qb * 128;
  const int bh = blockIdx.x;
  const int tid = threadIdx.x;
  const int wave = tid >> 6, lane = tid & 63, quad = lane >> 4, l15 = lane & 15;
  const _Float16* Q = qt + (size_t)bh * L_SEQ * HDIM;
  const _Float16* Kg = kt + (size_t)bh * L_SEQ * HDIM;
  const _Float16* Vg = vt + (size_t)bh * HDIM * L_SEQ;

  const float scale = 0.08838834764831845f;  // 1/sqrt(128)
  f16x8 qf[4];
  {
    int qrow = q0 + wave * 16 + l15;
    const _Float16 hs = (_Float16)scale;
    for (int kk = 0; kk < 4; ++kk) {
      qf[kk] = *(const f16x8*)(Q + (size_t)qrow * 128 + kk * 32 + quad * 8);
      for (int j = 0; j < 8; ++j) qf[kk][j] *= hs;  // fold 1/sqrt(d) into Q once
    }
  }
  f32x4 o[8] = {};
  float mi[4] = {-1e30f, -1e30f, -1e30f, -1e30f};
  float li[4] = {0.f, 0.f, 0.f, 0.f};
  const int ntile = 2 * qb + 2;

  // per-wave staging: 2 K gloads then 2 V gloads (order defines vmcnt ledger above)
  auto stageK = [&](int kv0) {
    for (int j = 0; j < 2; ++j) {
      int id = wave * 2 + j;
      gload16(Kg + (size_t)(kv0 + lane) * 128 + id * 8, (char*)Kl + id * 1024);
    }
  };
  auto stageV = [&](int kv0) {
    for (int j = 0; j < 2; ++j) {
      int id = wave * 2 + j;
      int kvb = id >> 1, h0 = (id & 1) * 64;
      gload16(Vg + (size_t)(h0 + lane) * L_SEQ + (kv0 + kvb * 8), (char*)Vl + (kvb * 128 + h0) * 16);
    }
  };

  stageK(0);
  stageV(0);

  for (int t = 0; t < ntile; ++t) {
    const int kv0 = t * 64;
    const bool more = (t + 1) < ntile;  // block-uniform

    // K_t landed (V_t still in flight), make visible block-wide
    asm volatile("s_waitcnt vmcnt(2)" ::: "memory");
    __builtin_amdgcn_sched_barrier(0);
    __builtin_amdgcn_s_barrier();

    // S = Q K^T  (16 x 64 per wave)
    f32x4 s[4] = {};
    {
      const f16x8* K8 = (const f16x8*)Kl;
      __builtin_amdgcn_s_setprio(1);
      for (int kk = 0; kk < 4; ++kk) {
        int hb = kk * 4 + quad;
        for (int ni = 0; ni < 4; ++ni) {
          f16x8 bfr = K8[hb * 64 + ni * 16 + l15];
          s[ni] = __builtin_amdgcn_mfma_f32_16x16x32_f16(qf[kk], bfr, s[ni], 0, 0, 0);
        }
      }
      __builtin_amdgcn_s_setprio(0);
    }
    __builtin_amdgcn_sched_barrier(0);
    __builtin_amdgcn_s_barrier();  // all waves done reading Kl
    __builtin_amdgcn_sched_barrier(0);
    if (more) stageK(kv0 + 64);  // latency hides under softmax below

    float mx[4];
    if (t >= ntile - 2) {
      // diagonal tiles: causal mask (Q pre-scaled, so no mul here)
      for (int reg = 0; reg < 4; ++reg) {
        int rowg = q0 + wave * 16 + quad * 4 + reg;
        float m = -1e30f;
        for (int ni = 0; ni < 4; ++ni) {
          float v = s[ni][reg];
          if ((kv0 + ni * 16 + l15) > rowg) v = -1e30f;
          s[ni][reg] = v;
          m = fmaxf(m, v);
        }
        mx[reg] = m;
      }
    } else {
      for (int reg = 0; reg < 4; ++reg)
        mx[reg] = fmaxf(fmaxf(s[0][reg], s[1][reg]), fmaxf(s[2][reg], s[3][reg]));
    }
    for (int off = 1; off < 16; off <<= 1)
      for (int reg = 0; reg < 4; ++reg)
        mx[reg] = fmaxf(mx[reg], __shfl_xor(mx[reg], off));
    // defer-max: only rescale when some row's max grew by > 8 (first tile always does)
    float dm = fmaxf(fmaxf(mx[0] - mi[0], mx[1] - mi[1]),
                     fmaxf(mx[2] - mi[2], mx[3] - mi[3]));
    if (!__all(dm <= 8.0f)) {
      for (int reg = 0; reg < 4; ++reg) {
        float mn = fmaxf(mi[reg], mx[reg]);
        float al = __expf(mi[reg] - mn);
        mi[reg] = mn;
        li[reg] *= al;
        for (int ni = 0; ni < 8; ++ni) o[ni][reg] *= al;
      }
    }
    float rs[4] = {0.f, 0.f, 0.f, 0.f};
    _Float16* Pw = Pl + wave * (16 * 64);
    for (int ni = 0; ni < 4; ++ni) {
      int kv = ni * 16 + l15;
      int pbase = ((kv >> 3) * 16) * 8 + (kv & 7);
      for (int reg = 0; reg < 4; ++reg) {
        float p = __expf(s[ni][reg] - mi[reg]);
        rs[reg] += p;
        Pw[pbase + (quad * 4 + reg) * 8] = (_Float16)p;
      }
    }
    for (int off = 1; off < 16; off <<= 1)
      for (int reg = 0; reg < 4; ++reg)
        rs[reg] += __shfl_xor(rs[reg], off);
    for (int reg = 0; reg < 4; ++reg) li[reg] += rs[reg];

    // V_t landed + own P writes done; make V visible block-wide
    if (more) {
      asm volatile("s_waitcnt vmcnt(2) lgkmcnt(0)" ::: "memory");
    } else {
      asm volatile("s_waitcnt vmcnt(0) lgkmcnt(0)" ::: "memory");
    }
    __builtin_amdgcn_sched_barrier(0);
    __builtin_amdgcn_s_barrier();

    {
      const f16x8* V8 = (const f16x8*)Vl;
      const f16x8* P8 = (const f16x8*)Pw;
      __builtin_amdgcn_s_setprio(1);
      for (int kk = 0; kk < 2; ++kk) {
        f16x8 pf = P8[(kk * 4 + quad) * 16 + l15];
        for (int ni = 0; ni < 8; ++ni) {
          f16x8 vf = V8[(kk * 4 + quad) * 128 + ni * 16 + l15];
          o[ni] = __builtin_amdgcn_mfma_f32_16x16x32_f16(pf, vf, o[ni], 0, 0, 0);
        }
      }
      __builtin_amdgcn_s_setprio(0);
    }
    __builtin_amdgcn_sched_barrier(0);
    __builtin_amdgcn_s_barrier();  // all waves done reading Vl
    __builtin_amdgcn_sched_barrier(0);
    if (more) stageV(kv0 + 64);  // latency hides under next tile's QK^T + softmax
  }
  // epilogue: O/l -> y in blocked layout: tile (gr>>7, col>>6), unit (((col&63)>>3)*128+(gr&127))*8+(col&7)
  int b = bh >> 4, h = bh & 15;
  for (int reg = 0; reg < 4; ++reg) {
    float inv = 1.f / li[reg];
    int gr = b * L_SEQ + q0 + wave * 16 + quad * 4 + reg;
    int mbt = gr >> 7, row = gr & 127;
    for (int ni = 0; ni < 8; ++ni) {
      int col = h * 128 + ni * 16 + l15;
      int cb = col >> 6, kb = (col >> 3) & 7, wi = col & 7;
      y[((size_t)mbt * 32 + cb) * 8192 + (size_t)(kb * 128 + row) * 8 + wi] =
          (_Float16)(o[ni][reg] * inv);
    }
  }
}

extern "C" void kernel_launch(void* const* d_in, const int* in_sizes, int n_in,
                              void* d_out, int out_size, void* d_ws, size_t ws_size,
                              hipStream_t stream) {
  const float* x = (const float*)d_in[0];      // [4,2048,2048]
  const float* w_qkv = (const float*)d_in[1];  // [6144,2048]
  const float* w_o = (const float*)d_in[2];    // [2048,2048]
  float* out = (float*)d_out;                  // [4,2048,2048]

  char* ws = (char*)d_ws;
  _Float16* xb = (_Float16*)ws;    ws += (size_t)8192 * 2048 * 2;   // 32 MiB blocked
  _Float16* wqkvb = (_Float16*)ws; ws += (size_t)6144 * 2048 * 2;   // 24 MiB blocked
  _Float16* wob = (_Float16*)ws;   ws += (size_t)2048 * 2048 * 2;   // 8 MiB blocked
  _Float16* qkv = (_Float16*)ws;   ws += (size_t)8192 * 6144 * 2;   // 96 MiB row-major
  _Float16* qt = (_Float16*)ws;    ws += (size_t)64 * 2048 * 128 * 2;
  _Float16* kt = (_Float16*)ws;    ws += (size_t)64 * 2048 * 128 * 2;
  _Float16* vt = (_Float16*)ws;    ws += (size_t)64 * 2048 * 128 * 2;
  _Float16* y = qkv;  // qkv dead after rope/v_transpose; y (blocked, 32 MiB) reuses it

  cvt_blocked<<<dim3(32, 64), 256, 0, stream>>>(x, xb, 2048);
  cvt_blocked<<<dim3(32, 48), 256, 0, stream>>>(w_qkv, wqkvb, 2048);
  cvt_blocked<<<dim3(32, 16), 256, 0, stream>>>(w_o, wob, 2048);

  // 256-sq tiles: gemm1 grid 32x24=768 blocks, gemm2 32x8=256 (both %8==0 for swizzle)
  gemm_bt<_Float16><<<dim3(768), 512, 0, stream>>>(xb, wqkvb, qkv, 8192, 6144, 2048);
  rope_scatter<<<dim3(8192, 8), 256, 0, stream>>>(qkv, qt, kt);
  v_transpose<<<dim3(32, 2, 64), 256, 0, stream>>>(qkv, vt);
  attn_fwd<<<dim3(64, 16), 512, 0, stream>>>(qt, kt, vt, y);
  gemm_bt<float><<<dim3(256), 512, 0, stream>>>(y, wob, out, 8192, 2048, 2048);
}

// Round 9
// 635.949 us; speedup vs baseline: 1.0178x; 1.0178x over previous
//
#include <hip/hip_runtime.h>

#define L_SEQ 2048
#define DMODEL 2048
#define NHEAD 16
#define HDIM 128
#define BATCH 4

typedef _Float16 f16x8 __attribute__((ext_vector_type(8)));
typedef _Float16 f16x4 __attribute__((ext_vector_type(4)));
typedef float f32x4 __attribute__((ext_vector_type(4)));

// async global->LDS, 16B per lane. LDS base must be wave-uniform; HW scatters lane*16.
__device__ __forceinline__ void gload16(const void* g, void* l) {
  __builtin_amdgcn_global_load_lds((const __attribute__((address_space(1))) void*)g,
                                   (__attribute__((address_space(3))) void*)l, 16, 0, 0);
}

// fp32 row-major [M][K] -> fp16 blocked tile-image layout:
// tile (mb, kt) of 128 rows x 64 k, stored contiguously (8192 halves = 16KB) in LDS image
// order: 16B-unit index (kb*128 + row), kb = (k&63)>>3, within-unit = k&7.
__global__ __launch_bounds__(256) void cvt_blocked(const float* __restrict__ in,
                                                   _Float16* __restrict__ out, int K) {
  const int kt = blockIdx.x, mb = blockIdx.y, KT = K >> 6;
  const int t = threadIdx.x, row = t >> 1, half = t & 1;
  const float* src = in + (size_t)(mb * 128 + row) * K + kt * 64 + half * 32;
  _Float16* tile = out + ((size_t)mb * KT + kt) * 8192;
  for (int j = 0; j < 4; ++j) {
    float4 a = *(const float4*)(src + j * 8);
    float4 b = *(const float4*)(src + j * 8 + 4);
    f16x8 o;
    o[0] = (_Float16)a.x; o[1] = (_Float16)a.y; o[2] = (_Float16)a.z; o[3] = (_Float16)a.w;
    o[4] = (_Float16)b.x; o[5] = (_Float16)b.y; o[6] = (_Float16)b.z; o[7] = (_Float16)b.w;
    int kb = half * 4 + j;
    *(f16x8*)(tile + (size_t)(kb * 128 + row) * 8) = o;
  }
}

// C[M][N] = A * Bt^T, A/Bt in BLOCKED tile-image layout (see cvt_blocked), C row-major.
// 128x128 tile, BK=64, 4 waves 2x2, each wave 64x64 via 4x4 mfma_16x16x32.
// R9: REVERTED to the R4-measured structure (191.6us, 1076 TF, MfmaUtil 55%, 3 blocks/CU).
// Pipelining post-mortems: R5 dbuf (64KB LDS, 2 blocks/CU) = 233us; R7 kk-split (1-phase
// prefetch distance) = 204us; R8 256^2-drain0 = 226us (m218: drain0 == 1-phase). The
// simple 2-barrier loop + 3-block TLP is the robust local optimum for this tile size.
template <typename OUT>
__global__ __launch_bounds__(256, 4) void gemm_bt(const _Float16* __restrict__ A,
                                                  const _Float16* __restrict__ Bt,
                                                  OUT* __restrict__ C,
                                                  int M, int N, int K) {
  __shared__ _Float16 As[128 * 64];
  __shared__ _Float16 Bs[128 * 64];
  const int KT = K >> 6;
  const int tid = threadIdx.x;
  const int wave = tid >> 6, lane = tid & 63, quad = lane >> 4, l15 = lane & 15;
  const int xcd = blockIdx.x & 7;
  const int lm = blockIdx.x >> 3;
  const int tm = xcd * 8 + (lm & 7);
  const int tn = lm >> 3;
  if (tm * 128 >= M || tn * 128 >= N) return;  // wave-uniform safety guard
  const int wm = (wave >> 1) * 64, wn = (wave & 1) * 64;
  const int id = wave * 4;
  f32x4 acc[4][4] = {};
  for (int kt = 0; kt < KT; ++kt) {
    const _Float16* tA = A + ((size_t)tm * KT + kt) * 8192;
    const _Float16* tB = Bt + ((size_t)tn * KT + kt) * 8192;
    __syncthreads();  // prev-iter LDS reads done before overwrite
    for (int j = 0; j < 4; ++j) {
      gload16(tA + (size_t)(id + j) * 512 + lane * 8, (char*)As + (id + j) * 1024);
      gload16(tB + (size_t)(id + j) * 512 + lane * 8, (char*)Bs + (id + j) * 1024);
    }
    __syncthreads();  // compiler drains vmcnt before barrier
    const f16x8* A8 = (const f16x8*)As;
    const f16x8* B8 = (const f16x8*)Bs;
    for (int kk = 0; kk < 2; ++kk) {
      int kb = kk * 4 + quad;
      f16x8 af[4], bf[4];
      for (int mi = 0; mi < 4; ++mi) af[mi] = A8[kb * 128 + wm + mi * 16 + l15];
      for (int ni = 0; ni < 4; ++ni) bf[ni] = B8[kb * 128 + wn + ni * 16 + l15];
      for (int mi = 0; mi < 4; ++mi)
        for (int ni = 0; ni < 4; ++ni)
          acc[mi][ni] = __builtin_amdgcn_mfma_f32_16x16x32_f16(af[mi], bf[ni], acc[mi][ni], 0, 0, 0);
    }
  }
  // C/D layout: col = lane&15, row = quad*4 + reg  (m89-verified, dtype-independent)
  for (int mi = 0; mi < 4; ++mi)
    for (int ni = 0; ni < 4; ++ni) {
      int r = tm * 128 + wm + mi * 16 + quad * 4;
      int c = tn * 128 + wn + ni * 16 + l15;
      for (int reg = 0; reg < 4; ++reg)
        C[(size_t)(r + reg) * N + c] = (OUT)acc[mi][ni][reg];
    }
}

// qkv[8192][6144] fp16, q/k part only -> rope -> qt,kt:[bh][l][hd]   (coalesced both sides)
__global__ void rope_scatter(const _Float16* __restrict__ qkv,
                             _Float16* __restrict__ qt,
                             _Float16* __restrict__ kt) {
  int row = blockIdx.x;                       // 0..8191 = b*2048 + l
  int pe = blockIdx.y * 256 + threadIdx.x;    // 0..2047 pair index (q,k only)
  int e = pe * 2;
  float x1 = (float)qkv[(size_t)row * 6144 + e];
  float x2 = (float)qkv[(size_t)row * 6144 + e + 1];
  int which = e >> 11;                        // 0=q, 1=k
  int h = (e >> 7) & 15;
  int hd = e & 127;
  int b = row >> 11, l = row & 2047;
  int bh = b * 16 + h;
  int i = hd >> 1;
  // freq = 10000^(-i/64) ; ln(10000)/64 = 0.14391156831212787
  float ang = (float)l * __expf((float)i * -0.14391156831212787f);
  float s, c;
  __sincosf(ang, &s, &c);
  float o1 = x1 * c - x2 * s;
  float o2 = x2 * c + x1 * s;
  _Float16* dst = (which == 0) ? qt : kt;
  size_t base = ((size_t)bh * 2048 + l) * 128 + hd;
  dst[base] = (_Float16)o1;
  dst[base + 1] = (_Float16)o2;
}

// V part of qkv -> vt[bh][hd][l], LDS-tiled 64x64 transpose, coalesced global R/W.
__global__ __launch_bounds__(256) void v_transpose(const _Float16* __restrict__ qkv,
                                                   _Float16* __restrict__ vt) {
  __shared__ _Float16 Ls[64 * 72];
  const int tid = threadIdx.x;
  const int l0 = blockIdx.x * 64;       // 32 tiles
  const int hd0 = blockIdx.y * 64;      // 2 tiles
  const int bh = blockIdx.z;            // 64
  const int b = bh >> 4, h = bh & 15;
  const size_t colbase = 4096 + h * 128 + hd0;
  for (int i = 0; i < 2; ++i) {
    int chunk = tid + i * 256;
    int r = chunk >> 3, c = chunk & 7;
    f16x8 v = *(const f16x8*)(qkv + (size_t)(b * 2048 + l0 + r) * 6144 + colbase + c * 8);
    *(f16x8*)(Ls + r * 72 + c * 8) = v;
  }
  __syncthreads();
  for (int i = 0; i < 2; ++i) {
    int chunk = tid + i * 256;
    int hr = chunk >> 3, c = chunk & 7;
    f16x8 o;
    for (int j = 0; j < 8; ++j) o[j] = Ls[(c * 8 + j) * 72 + hr];
    *(f16x8*)(vt + ((size_t)bh * 128 + hd0 + hr) * 2048 + l0 + c * 8) = o;
  }
}

// Flash attention, causal. 8-wave blocks, 128 q rows, KV tiles of 64.
// Grid (64,16) (bh fast-moving) + mod-4-balanced perm (68 tile-units/CU exact), longest
// classes first. R9 VALU trims:
//  (a) row-sum via ones-MFMA: li's per-tile sum was 16 shfl_xor (DS ops) + 16 adds; the
//      PV A-fragments pf ARE P in MFMA layout, so rsd = mfma(pf, ones, rsd) yields the
//      row-sum (col-replicated) for 2 extra MFMA. li += rsd after PV (rescale happens
//      before the add, numerically identical to the old order).
//  (b) exp2 folding: Q pre-scale now scale*log2e; p = exp2f(s-mi), al = exp2f(mi-mn),
//      defer-max THR 8 -> 11.544 (same e^8 bound). v_exp_f32 IS 2^x -> kills 16 muls/tile.
// Per-wave vmcnt ledger (2 K + 2 V gloads per wave per tile, K before V):
//   loop top: [K_t(2), V_t(2)]          -> vmcnt(2) = K_t landed
//   mid (after stageK(t+1)): [V_t(2), K_t+1(2)] -> vmcnt(2) = V_t landed (last tile: 0)
//   end (after stageV(t+1)): [K_t+1(2), V_t+1(2)] -> loop-top invariant
__global__ __launch_bounds__(512, 4) void attn_fwd(const _Float16* __restrict__ qt,
                                                   const _Float16* __restrict__ kt,
                                                   const _Float16* __restrict__ vt,
                                                   _Float16* __restrict__ y) {
  __shared__ _Float16 Kl[64 * 128];      // 16KB
  __shared__ _Float16 Vl[64 * 128];      // 16KB
  __shared__ _Float16 Pl[8 * 16 * 64];   // 16KB
  const int a = blockIdx.y >> 2, bq = blockIdx.y & 3;
  const int qb = (a == 0) ? 15 - bq : (a == 1) ? 8 + bq : (a == 2) ? 4 + bq : 3 - bq;
  const int q0 = qb * 128;
  const int bh = blockIdx.x;
  const int tid = threadIdx.x;
  const int wave = tid >> 6, lane = tid & 63, quad = lane >> 4, l15 = lane & 15;
  const _Float16* Q = qt + (size_t)bh * L_SEQ * HDIM;
  const _Float16* Kg = kt + (size_t)bh * L_SEQ * HDIM;
  const _Float16* Vg = vt + (size_t)bh * HDIM * L_SEQ;

  // scale * log2(e): logits in log2 units -> exp2 everywhere (v_exp_f32 is 2^x)
  f16x8 qf[4];
  {
    int qrow = q0 + wave * 16 + l15;
    const _Float16 hs = (_Float16)(0.08838834764831845f * 1.4426950408889634f);
    for (int kk = 0; kk < 4; ++kk) {
      qf[kk] = *(const f16x8*)(Q + (size_t)qrow * 128 + kk * 32 + quad * 8);
      for (int j = 0; j < 8; ++j) qf[kk][j] *= hs;
    }
  }
  f16x8 ones;
  for (int j = 0; j < 8; ++j) ones[j] = (_Float16)1.0f;
  f32x4 o[8] = {};
  float mi[4] = {-1e30f, -1e30f, -1e30f, -1e30f};
  float li[4] = {0.f, 0.f, 0.f, 0.f};
  const int ntile = 2 * qb + 2;

  // per-wave staging: 2 K gloads then 2 V gloads (order defines vmcnt ledger above)
  auto stageK = [&](int kv0) {
    for (int j = 0; j < 2; ++j) {
      int id = wave * 2 + j;
      gload16(Kg + (size_t)(kv0 + lane) * 128 + id * 8, (char*)Kl + id * 1024);
    }
  };
  auto stageV = [&](int kv0) {
    for (int j = 0; j < 2; ++j) {
      int id = wave * 2 + j;
      int kvb = id >> 1, h0 = (id & 1) * 64;
      gload16(Vg + (size_t)(h0 + lane) * L_SEQ + (kv0 + kvb * 8), (char*)Vl + (kvb * 128 + h0) * 16);
    }
  };

  stageK(0);
  stageV(0);

  for (int t = 0; t < ntile; ++t) {
    const int kv0 = t * 64;
    const bool more = (t + 1) < ntile;  // block-uniform

    // K_t landed (V_t still in flight), make visible block-wide
    asm volatile("s_waitcnt vmcnt(2)" ::: "memory");
    __builtin_amdgcn_sched_barrier(0);
    __builtin_amdgcn_s_barrier();

    // S = Q K^T  (16 x 64 per wave)
    f32x4 s[4] = {};
    {
      const f16x8* K8 = (const f16x8*)Kl;
      __builtin_amdgcn_s_setprio(1);
      for (int kk = 0; kk < 4; ++kk) {
        int hb = kk * 4 + quad;
        for (int ni = 0; ni < 4; ++ni) {
          f16x8 bfr = K8[hb * 64 + ni * 16 + l15];
          s[ni] = __builtin_amdgcn_mfma_f32_16x16x32_f16(qf[kk], bfr, s[ni], 0, 0, 0);
        }
      }
      __builtin_amdgcn_s_setprio(0);
    }
    __builtin_amdgcn_sched_barrier(0);
    __builtin_amdgcn_s_barrier();  // all waves done reading Kl
    __builtin_amdgcn_sched_barrier(0);
    if (more) stageK(kv0 + 64);  // latency hides under softmax below

    float mx[4];
    if (t >= ntile - 2) {
      // diagonal tiles: causal mask (scale folded into Q)
      for (int reg = 0; reg < 4; ++reg) {
        int rowg = q0 + wave * 16 + quad * 4 + reg;
        float m = -1e30f;
        for (int ni = 0; ni < 4; ++ni) {
          float v = s[ni][reg];
          if ((kv0 + ni * 16 + l15) > rowg) v = -1e30f;
          s[ni][reg] = v;
          m = fmaxf(m, v);
        }
        mx[reg] = m;
      }
    } else {
      for (int reg = 0; reg < 4; ++reg)
        mx[reg] = fmaxf(fmaxf(s[0][reg], s[1][reg]), fmaxf(s[2][reg], s[3][reg]));
    }
    for (int off = 1; off < 16; off <<= 1)
      for (int reg = 0; reg < 4; ++reg)
        mx[reg] = fmaxf(mx[reg], __shfl_xor(mx[reg], off));
    // defer-max: rescale only when max grew > 8 ln-units = 11.544 log2-units
    float dm = fmaxf(fmaxf(mx[0] - mi[0], mx[1] - mi[1]),
                     fmaxf(mx[2] - mi[2], mx[3] - mi[3]));
    if (!__all(dm <= 11.544f)) {
      for (int reg = 0; reg < 4; ++reg) {
        float mn = fmaxf(mi[reg], mx[reg]);
        float al = exp2f(mi[reg] - mn);
        mi[reg] = mn;
        li[reg] *= al;
        for (int ni = 0; ni < 8; ++ni) o[ni][reg] *= al;
      }
    }
    _Float16* Pw = Pl + wave * (16 * 64);
    for (int ni = 0; ni < 4; ++ni) {
      int kv = ni * 16 + l15;
      int pbase = ((kv >> 3) * 16) * 8 + (kv & 7);
      for (int reg = 0; reg < 4; ++reg) {
        float p = exp2f(s[ni][reg] - mi[reg]);
        Pw[pbase + (quad * 4 + reg) * 8] = (_Float16)p;
      }
    }

    // V_t landed + own P writes done; make V visible block-wide
    if (more) {
      asm volatile("s_waitcnt vmcnt(2) lgkmcnt(0)" ::: "memory");
    } else {
      asm volatile("s_waitcnt vmcnt(0) lgkmcnt(0)" ::: "memory");
    }
    __builtin_amdgcn_sched_barrier(0);
    __builtin_amdgcn_s_barrier();

    {
      const f16x8* V8 = (const f16x8*)Vl;
      const f16x8* P8 = (const f16x8*)Pw;
      f32x4 rsd = {};  // tile row-sum via ones-MFMA (replaces 16 shfl + 16 add)
      __builtin_amdgcn_s_setprio(1);
      for (int kk = 0; kk < 2; ++kk) {
        f16x8 pf = P8[(kk * 4 + quad) * 16 + l15];
        rsd = __builtin_amdgcn_mfma_f32_16x16x32_f16(pf, ones, rsd, 0, 0, 0);
        for (int ni = 0; ni < 8; ++ni) {
          f16x8 vf = V8[(kk * 4 + quad) * 128 + ni * 16 + l15];
          o[ni] = __builtin_amdgcn_mfma_f32_16x16x32_f16(pf, vf, o[ni], 0, 0, 0);
        }
      }
      __builtin_amdgcn_s_setprio(0);
      for (int reg = 0; reg < 4; ++reg) li[reg] += rsd[reg];
    }
    __builtin_amdgcn_sched_barrier(0);
    __builtin_amdgcn_s_barrier();  // all waves done reading Vl
    __builtin_amdgcn_sched_barrier(0);
    if (more) stageV(kv0 + 64);  // latency hides under next tile's QK^T + softmax
  }
  // epilogue: O/l -> y in blocked layout: tile (gr>>7, col>>6), unit (((col&63)>>3)*128+(gr&127))*8+(col&7)
  int b = bh >> 4, h = bh & 15;
  for (int reg = 0; reg < 4; ++reg) {
    float inv = 1.f / li[reg];
    int gr = b * L_SEQ + q0 + wave * 16 + quad * 4 + reg;
    int mbt = gr >> 7, row = gr & 127;
    for (int ni = 0; ni < 8; ++ni) {
      int col = h * 128 + ni * 16 + l15;
      int cb = col >> 6, kb = (col >> 3) & 7, wi = col & 7;
      y[((size_t)mbt * 32 + cb) * 8192 + (size_t)(kb * 128 + row) * 8 + wi] =
          (_Float16)(o[ni][reg] * inv);
    }
  }
}

extern "C" void kernel_launch(void* const* d_in, const int* in_sizes, int n_in,
                              void* d_out, int out_size, void* d_ws, size_t ws_size,
                              hipStream_t stream) {
  const float* x = (const float*)d_in[0];      // [4,2048,2048]
  const float* w_qkv = (const float*)d_in[1];  // [6144,2048]
  const float* w_o = (const float*)d_in[2];    // [2048,2048]
  float* out = (float*)d_out;                  // [4,2048,2048]

  char* ws = (char*)d_ws;
  _Float16* xb = (_Float16*)ws;    ws += (size_t)8192 * 2048 * 2;   // 32 MiB blocked
  _Float16* wqkvb = (_Float16*)ws; ws += (size_t)6144 * 2048 * 2;   // 24 MiB blocked
  _Float16* wob = (_Float16*)ws;   ws += (size_t)2048 * 2048 * 2;   // 8 MiB blocked
  _Float16* qkv = (_Float16*)ws;   ws += (size_t)8192 * 6144 * 2;   // 96 MiB row-major
  _Float16* qt = (_Float16*)ws;    ws += (size_t)64 * 2048 * 128 * 2;
  _Float16* kt = (_Float16*)ws;    ws += (size_t)64 * 2048 * 128 * 2;
  _Float16* vt = (_Float16*)ws;    ws += (size_t)64 * 2048 * 128 * 2;
  _Float16* y = qkv;  // qkv dead after rope/v_transpose; y (blocked, 32 MiB) reuses it

  cvt_blocked<<<dim3(32, 64), 256, 0, stream>>>(x, xb, 2048);
  cvt_blocked<<<dim3(32, 48), 256, 0, stream>>>(w_qkv, wqkvb, 2048);
  cvt_blocked<<<dim3(32, 16), 256, 0, stream>>>(w_o, wob, 2048);

  gemm_bt<_Float16><<<dim3(48 * 64), 256, 0, stream>>>(xb, wqkvb, qkv, 8192, 6144, 2048);
  rope_scatter<<<dim3(8192, 8), 256, 0, stream>>>(qkv, qt, kt);
  v_transpose<<<dim3(32, 2, 64), 256, 0, stream>>>(qkv, vt);
  attn_fwd<<<dim3(64, 16), 512, 0, stream>>>(qt, kt, vt, y);
  gemm_bt<float><<<dim3(16 * 64), 256, 0, stream>>>(y, wob, out, 8192, 2048, 2048);
}